// Round 7
// baseline (44.573 us; speedup 1.0000x reference)
//
#include <hip/hip_runtime.h>
#include <math.h>

#define NN 320
#define DFULL 129            // 1 time dim + 128 spatial
#define MIN_DIST_F 0.1f
#define MARGIN_F 0.1f
#define WEIGHT_F 0.1f

// ---------------- Single fused kernel: Gram row + loss + gated finalize ----------------
// Block = anchor i (320 blocks x 320 threads).
// Phase A: emb row i via 16-lane group dots (coalesced 64B-line reads of E; E read
//          exactly once per block -> 53 MB L2 chip-wide, no amplification).
// Phase B: ordered-pair violations; k = tid in registers, j-loop = wave-uniform LDS
//          broadcast. NaN-poisoned e kills invalid pairs via NaN-safe cndmask adds
//          (never multiply-by-flag: 0*NaN=NaN). Self-pair (exactly MARGIN) removed.
// Phase C: per-block partial via atomicExch (coherent-point write), release fence,
//          gate atomicAdd; 320th arriver reduces all partials and writes out.
//          Gate is zeroed by a hipMemsetAsync node each launch -> deterministic.
__global__ __launch_bounds__(NN) void fused_kernel(const float* __restrict__ E,
                                                   const float* __restrict__ gt,
                                                   unsigned* __restrict__ gate,
                                                   float* __restrict__ pT,
                                                   float* __restrict__ pC,
                                                   float* __restrict__ out) {
    const int i = blockIdx.x;
    const int t = threadIdx.x;
    const int g = t >> 4;      // group 0..19
    const int q = t & 15;      // lane within group

    __shared__ float  sEi[DFULL];
    __shared__ float2 sge[NN];             // (e or NaN, gt value)
    __shared__ float  wt[5], wc[5];
    __shared__ int    sWinner;

    if (t < DFULL) sEi[t] = E[i * DFULL + t];
    sge[t] = make_float2(0.0f, gt[i * NN + t]);   // coalesced gt row stage
    __syncthreads();

    const float e0   = sEi[0];
    const float e128 = sEi[128];

    // ---- Phase A: group g computes dots for j = g, g+20, ..., g+300 ----
    for (int j = g; j < NN; j += 20) {
        const float* __restrict__ Ej = E + j * DFULL;
        float S = 0.0f;
        #pragma unroll
        for (int u = 0; u < 8; ++u) {      // d = q + 16u  (covers 0..127)
            const int d = q + (u << 4);
            S = fmaf(sEi[d], Ej[d], S);
        }
        S += __shfl_xor(S, 1, 64);
        S += __shfl_xor(S, 2, 64);
        S += __shfl_xor(S, 4, 64);
        S += __shfl_xor(S, 8, 64);         // S = sum_{d=0..127} E_i[d]*E_j[d]
        if (q == 0) {
            // -inner = t_i t_j - sp_i.sp_j = 2*E_i0*E_j0 - S - E_i128*E_j128
            float x = fmaf(2.0f * e0, Ej[0], -S) - e128 * Ej[128];
            x = fmaxf(x, 1.0f + 1e-7f);
            float e  = acoshf(x);
            float gv = sge[j].y;
            bool valid = (gv >= MIN_DIST_F) && (j != i);
            sge[j].x = valid ? e : __builtin_nanf("");
        }
    }
    __syncthreads();

    // ---- Phase B: ordered-pair loss; this thread owns k = t ----
    const float2 me = sge[t];
    const float ek = me.x, gk = me.y;      // ek NaN iff k invalid for anchor i
    float tot = 0.0f, cnt = 0.0f;
    #pragma unroll 8
    for (int j = 0; j < NN; ++j) {
        float2 u = sge[j];                 // wave-uniform LDS broadcast
        float d  = gk - u.y;
        float s  = copysignf(1.0f, d);
        float v  = fmaf(s, u.x - ek, MARGIN_F);   // NaN if either side invalid
        bool p   = v > 0.0f;                      // false for NaN
        tot += p ? v : 0.0f;
        cnt += p ? 1.0f : 0.0f;
    }
    if (ek == ek) { tot -= MARGIN_F; cnt -= 1.0f; }   // self-pair j==k (= MARGIN)

    // block reduce (5 waves)
    for (int off = 32; off > 0; off >>= 1) {
        tot += __shfl_down(tot, off, 64);
        cnt += __shfl_down(cnt, off, 64);
    }
    const int lane = t & 63, wid = t >> 6;
    if (lane == 0) { wt[wid] = tot; wc[wid] = cnt; }
    __syncthreads();

    // ---- Phase C: gated single-pass finalize ----
    if (t == 0) {
        float T = wt[0] + wt[1] + wt[2] + wt[3] + wt[4];
        float C = wc[0] + wc[1] + wc[2] + wc[3] + wc[4];
        atomicExch(&pT[i], T);             // coherent-point stores
        atomicExch(&pC[i], C);
        __threadfence();                   // release
        unsigned old = atomicAdd(gate, 1u);
        sWinner = (old == (unsigned)(NN - 1)) ? 1 : 0;
    }
    __syncthreads();
    if (sWinner) {
        __threadfence();                   // acquire
        float T = atomicAdd(&pT[t], 0.0f); // atomic loads (coherent point)
        float C = atomicAdd(&pC[t], 0.0f);
        for (int off = 32; off > 0; off >>= 1) {
            T += __shfl_down(T, off, 64);
            C += __shfl_down(C, off, 64);
        }
        if (lane == 0) { wt[wid] = T; wc[wid] = C; }
        __syncthreads();
        if (t == 0) {
            float Tt = wt[0] + wt[1] + wt[2] + wt[3] + wt[4];
            float Ct = wc[0] + wc[1] + wc[2] + wc[3] + wc[4];
            out[0] = (Ct > 0.0f) ? WEIGHT_F * Tt / Ct : 0.0f;
        }
    }
}

extern "C" void kernel_launch(void* const* d_in, const int* in_sizes, int n_in,
                              void* d_out, int out_size, void* d_ws, size_t ws_size,
                              hipStream_t stream) {
    const float* E  = (const float*)d_in[0];   // embeddings (320 x 129)
    const float* gt = (const float*)d_in[1];   // tree_distances (320 x 320)
    float* out = (float*)d_out;
    unsigned* gate = (unsigned*)d_ws;                       // 4 B, zeroed each launch
    float* pT = (float*)((char*)d_ws + 256);                // 320 f32
    float* pC = (float*)((char*)d_ws + 256 + NN * 4);       // 320 f32

    hipMemsetAsync(gate, 0, sizeof(unsigned), stream);
    fused_kernel<<<NN, NN, 0, stream>>>(E, gt, gate, pT, pC, out);
}

// Round 8
// 29.670 us; speedup vs baseline: 1.5023x; 1.5023x over previous
//
#include <hip/hip_runtime.h>
#include <math.h>

#define NN 320
#define DFULL 129            // 1 time dim + 128 spatial
#define MIN_DIST_F 0.1f
#define MARGIN_F 0.1f
#define WEIGHT_F 0.1f
#define NTILE 20             // 320/16
#define NTRI (NTILE*(NTILE+1)/2)  // 210 triangular tiles
#define JLEN 80              // j-chunk length
#define NUNITS 6400          // 320 anchors * 5 kgroups * 4 jchunks
#define LBLK 256             // loss blocks
#define LTHR 512             // loss threads = 8 waves
#define NWAVE (LBLK*(LTHR/64))    // 2048 waves grid-wide

// ---------------- Kernel 1: Lorentz distances, NaN-poisoned, symmetric ----------------
// embp[i][j] = valid(i,j) ? acosh(clip(-<E_i,E_j>_L)) : NaN ; also zeroes the gate
// (kernel-boundary ordering makes it visible to kernel 2 -- replaces hipMemsetAsync,
// which profiling showed costs ~39us as a graph node).
__device__ __forceinline__ int tri_off(int a) { return a * NTILE - (a * (a - 1)) / 2; }

__global__ __launch_bounds__(256) void lorentz_kernel(const float* __restrict__ E,
                                                      const float* __restrict__ gt,
                                                      float* __restrict__ embp,
                                                      unsigned* __restrict__ gate) {
    if (blockIdx.x == 0 && threadIdx.x == 0) *gate = 0u;
    // decode triangular tile (a <= b)
    const int t = blockIdx.x;
    float fa = (2.0f * NTILE + 1.0f - sqrtf((2.0f*NTILE+1.0f)*(2.0f*NTILE+1.0f) - 8.0f * (float)t)) * 0.5f;
    int a = (int)fa;
    if (a > 0 && tri_off(a) > t) --a;
    if (tri_off(a + 1) <= t) ++a;
    const int b = a + (t - tri_off(a));
    const int i0 = a * 16, j0 = b * 16;

    __shared__ float As[16][DFULL];
    __shared__ float Bs[16][DFULL];
    for (int q = threadIdx.x; q < 16 * DFULL; q += 256) {
        int r = q / DFULL, c = q - r * DFULL;
        As[r][c] = E[(i0 + r) * DFULL + c];
        Bs[r][c] = E[(j0 + r) * DFULL + c];
    }
    __syncthreads();
    const int ti = threadIdx.x & 15;
    const int tj = threadIdx.x >> 4;
    const int i = i0 + tj, j = j0 + ti;
    float tt = As[tj][0] * Bs[ti][0];
    float ss = 0.0f;
    #pragma unroll
    for (int d = 1; d < DFULL; ++d) ss = fmaf(As[tj][d], Bs[ti][d], ss);
    float x = fmaxf(tt - ss, 1.0f + 1e-7f);
    float e = acoshf(x);
    float g = gt[i * NN + j];
    float ep = (g >= MIN_DIST_F && i != j) ? e : __builtin_nanf("");
    embp[i * NN + j] = ep;   // symmetric; diagonal tiles double-write same value (benign)
    embp[j * NN + i] = ep;
}

// ---------------- Kernel 2: loss over 6400 one-wave units + gated finalize ----------------
// Unit (i,kg,jc): lane owns k = kg*64+lane; j in [jc*80, jc*80+80).
// NaN-poisoned embp kills invalid pairs: v NaN -> (v>0) false -> cndmask adds 0
// (never multiply-by-flag: 0*NaN=NaN). count accumulates wave-uniformly via
// __popcll(__ballot(p)) (SALU, overlaps VALU; no lane reduce needed).
// Self-pair j==k (exactly MARGIN) removed per-lane / per-ballot.
// Finalize: round-6 proven gate protocol (256 arrivals), winner reduces partials.
__global__ __launch_bounds__(LTHR) void loss_kernel(const float* __restrict__ embp,
                                                    const float* __restrict__ gt,
                                                    unsigned* __restrict__ gate,
                                                    float* __restrict__ pT,
                                                    float* __restrict__ pC,
                                                    float* __restrict__ out) {
    const int lane = threadIdx.x & 63;
    const int wid  = threadIdx.x >> 6;
    const int gw   = blockIdx.x * (LTHR / 64) + wid;   // global wave id 0..2047

    float tot = 0.0f;      // per-lane
    int   cnt = 0;         // wave-uniform (ballot-popcount)

    for (int unit = gw; unit < NUNITS; unit += NWAVE) {
        const int i  = unit / 20;
        const int r  = unit - i * 20;
        const int kg = r >> 2;
        const int jc = r & 3;
        const int k  = (kg << 6) + lane;
        const float* __restrict__ erow = embp + i * NN;
        const float* __restrict__ grow = gt   + i * NN;
        const float ek = erow[k];          // NaN if k invalid for anchor i
        const float gk = grow[k];
        const int j0 = jc * JLEN;

        #pragma unroll 4
        for (int jb = 0; jb < JLEN; jb += 4) {
            const float4 e4 = *reinterpret_cast<const float4*>(erow + j0 + jb);
            const float4 g4 = *reinterpret_cast<const float4*>(grow + j0 + jb);
            {   float d = gk - g4.x; float v = fmaf(copysignf(1.0f, d), e4.x - ek, MARGIN_F);
                bool p = v > 0.0f; tot += p ? v : 0.0f; cnt += (int)__popcll(__ballot(p)); }
            {   float d = gk - g4.y; float v = fmaf(copysignf(1.0f, d), e4.y - ek, MARGIN_F);
                bool p = v > 0.0f; tot += p ? v : 0.0f; cnt += (int)__popcll(__ballot(p)); }
            {   float d = gk - g4.z; float v = fmaf(copysignf(1.0f, d), e4.z - ek, MARGIN_F);
                bool p = v > 0.0f; tot += p ? v : 0.0f; cnt += (int)__popcll(__ballot(p)); }
            {   float d = gk - g4.w; float v = fmaf(copysignf(1.0f, d), e4.w - ek, MARGIN_F);
                bool p = v > 0.0f; tot += p ? v : 0.0f; cnt += (int)__popcll(__ballot(p)); }
        }
        // self-pair removal: lane with k in [j0,j0+80) and ek valid contributed exactly MARGIN
        bool self = (ek == ek) && (k >= j0) && (k < j0 + JLEN);
        tot -= self ? MARGIN_F : 0.0f;
        cnt -= (int)__popcll(__ballot(self));
    }

    // lane reduce (tot only; cnt is wave-uniform)
    for (int off = 32; off > 0; off >>= 1) tot += __shfl_down(tot, off, 64);

    __shared__ float wt[LTHR / 64];
    __shared__ int   wc[LTHR / 64];
    __shared__ int   sWinner;
    if (lane == 0) { wt[wid] = tot; wc[wid] = cnt; }
    __syncthreads();

    if (threadIdx.x == 0) {
        float T = 0.0f; int C = 0;
        #pragma unroll
        for (int w = 0; w < LTHR / 64; ++w) { T += wt[w]; C += wc[w]; }
        atomicExch(&pT[blockIdx.x], T);
        atomicExch(&pC[blockIdx.x], (float)C);
        __threadfence();                         // release
        unsigned old = atomicAdd(gate, 1u);
        sWinner = (old == (unsigned)(LBLK - 1)) ? 1 : 0;
    }
    __syncthreads();

    if (sWinner) {
        __threadfence();                         // acquire
        float T = 0.0f, C = 0.0f;
        if (threadIdx.x < LBLK) {
            T = atomicAdd(&pT[threadIdx.x], 0.0f);   // atomic loads (coherent point)
            C = atomicAdd(&pC[threadIdx.x], 0.0f);
        }
        for (int off = 32; off > 0; off >>= 1) {
            T += __shfl_down(T, off, 64);
            C += __shfl_down(C, off, 64);
        }
        __shared__ float ft[LTHR / 64], fc[LTHR / 64];
        if (lane == 0) { ft[wid] = T; fc[wid] = C; }
        __syncthreads();
        if (threadIdx.x == 0) {
            float Tt = 0.0f, Ct = 0.0f;
            #pragma unroll
            for (int w = 0; w < LTHR / 64; ++w) { Tt += ft[w]; Ct += fc[w]; }
            out[0] = (Ct > 0.0f) ? WEIGHT_F * Tt / Ct : 0.0f;
        }
    }
}

extern "C" void kernel_launch(void* const* d_in, const int* in_sizes, int n_in,
                              void* d_out, int out_size, void* d_ws, size_t ws_size,
                              hipStream_t stream) {
    const float* E  = (const float*)d_in[0];   // embeddings (320 x 129)
    const float* gt = (const float*)d_in[1];   // tree_distances (320 x 320)
    float* out = (float*)d_out;
    unsigned* gate = (unsigned*)d_ws;                         // 4 B, zeroed by kernel 1
    float* pT = (float*)((char*)d_ws + 256);                  // 256 f32
    float* pC = (float*)((char*)d_ws + 256 + LBLK * 4);       // 256 f32
    float* embp = (float*)((char*)d_ws + 4096);               // 320*320 f32 = 400 KB

    lorentz_kernel<<<NTRI, 256, 0, stream>>>(E, gt, embp, gate);
    loss_kernel<<<LBLK, LTHR, 0, stream>>>(embp, gt, gate, pT, pC, out);
}

// Round 9
// 28.229 us; speedup vs baseline: 1.5790x; 1.0511x over previous
//
#include <hip/hip_runtime.h>
#include <math.h>

#define NN 320
#define DFULL 129            // 1 time dim + 128 spatial
#define MIN_DIST_F 0.1f
#define MARGIN_F 0.1f
#define WEIGHT_F 0.1f
#define NTILE 20             // 320/16
#define NTRI (NTILE*(NTILE+1)/2)  // 210 triangular tiles
#define JLEN 80              // j-chunk length
#define NUNITS 6400          // 320 anchors * 5 kgroups * 4 jchunks
#define LBLK 256             // loss blocks
#define LTHR 1024            // loss threads = 16 waves -> 4 waves/SIMD (latency hiding)
#define NWAVE (LBLK*(LTHR/64))    // 4096 waves grid-wide

// ---------------- Kernel 1: Lorentz distances, NaN-poisoned, symmetric ----------------
// embp[i][j] = valid(i,j) ? acosh(clip(-<E_i,E_j>_L)) : NaN ; also zeroes the gate
// (kernel-boundary ordering makes it visible to kernel 2 -- replaces hipMemsetAsync,
// which profiling showed costs ~39us as a graph node).
__device__ __forceinline__ int tri_off(int a) { return a * NTILE - (a * (a - 1)) / 2; }

__global__ __launch_bounds__(256) void lorentz_kernel(const float* __restrict__ E,
                                                      const float* __restrict__ gt,
                                                      float* __restrict__ embp,
                                                      unsigned* __restrict__ gate) {
    if (blockIdx.x == 0 && threadIdx.x == 0) *gate = 0u;
    // decode triangular tile (a <= b)
    const int t = blockIdx.x;
    float fa = (2.0f * NTILE + 1.0f - sqrtf((2.0f*NTILE+1.0f)*(2.0f*NTILE+1.0f) - 8.0f * (float)t)) * 0.5f;
    int a = (int)fa;
    if (a > 0 && tri_off(a) > t) --a;
    if (tri_off(a + 1) <= t) ++a;
    const int b = a + (t - tri_off(a));
    const int i0 = a * 16, j0 = b * 16;

    __shared__ float As[16][DFULL];
    __shared__ float Bs[16][DFULL];
    for (int q = threadIdx.x; q < 16 * DFULL; q += 256) {
        int r = q / DFULL, c = q - r * DFULL;
        As[r][c] = E[(i0 + r) * DFULL + c];
        Bs[r][c] = E[(j0 + r) * DFULL + c];
    }
    __syncthreads();
    const int ti = threadIdx.x & 15;
    const int tj = threadIdx.x >> 4;
    const int i = i0 + tj, j = j0 + ti;
    float tt = As[tj][0] * Bs[ti][0];
    float ss = 0.0f;
    #pragma unroll
    for (int d = 1; d < DFULL; ++d) ss = fmaf(As[tj][d], Bs[ti][d], ss);
    float x = fmaxf(tt - ss, 1.0f + 1e-7f);
    float e = acoshf(x);
    float g = gt[i * NN + j];
    float ep = (g >= MIN_DIST_F && i != j) ? e : __builtin_nanf("");
    embp[i * NN + j] = ep;   // symmetric; diagonal tiles double-write same value (benign)
    embp[j * NN + i] = ep;
}

// ---------------- Kernel 2: loss over 6400 one-wave units + gated finalize ----------------
// Unit (i,kg,jc): lane owns k = kg*64+lane; j in [jc*80, jc*80+80).
// NaN-poisoned embp kills invalid pairs: v NaN -> (v>0) false -> cndmask adds 0
// (never multiply-by-flag: 0*NaN=NaN). count accumulates wave-uniformly via
// __popcll(__ballot(p)) (SALU, overlaps VALU; no lane reduce needed).
// Self-pair j==k (exactly MARGIN) removed per-lane / per-ballot.
// 16 waves/block = 4 waves/SIMD + unroll-8 ILP hide the broadcast-load latency
// (round-7 regression root cause: 2 waves/SIMD + unroll 4 exposed ~200-900cy loads).
__global__ __launch_bounds__(LTHR) void loss_kernel(const float* __restrict__ embp,
                                                    const float* __restrict__ gt,
                                                    unsigned* __restrict__ gate,
                                                    float* __restrict__ pT,
                                                    float* __restrict__ pC,
                                                    float* __restrict__ out) {
    const int lane = threadIdx.x & 63;
    const int wid  = threadIdx.x >> 6;
    const int gw   = blockIdx.x * (LTHR / 64) + wid;   // global wave id 0..4095

    float tot = 0.0f;      // per-lane
    int   cnt = 0;         // wave-uniform (ballot-popcount)

    for (int unit = gw; unit < NUNITS; unit += NWAVE) {
        const int i  = unit / 20;
        const int r  = unit - i * 20;
        const int kg = r >> 2;
        const int jc = r & 3;
        const int k  = (kg << 6) + lane;
        const float* __restrict__ erow = embp + i * NN;
        const float* __restrict__ grow = gt   + i * NN;
        const float ek = erow[k];          // NaN if k invalid for anchor i
        const float gk = grow[k];
        const int j0 = jc * JLEN;

        #pragma unroll 8
        for (int jb = 0; jb < JLEN; jb += 4) {
            const float4 e4 = *reinterpret_cast<const float4*>(erow + j0 + jb);
            const float4 g4 = *reinterpret_cast<const float4*>(grow + j0 + jb);
            {   float d = gk - g4.x; float v = fmaf(copysignf(1.0f, d), e4.x - ek, MARGIN_F);
                bool p = v > 0.0f; tot += p ? v : 0.0f; cnt += (int)__popcll(__ballot(p)); }
            {   float d = gk - g4.y; float v = fmaf(copysignf(1.0f, d), e4.y - ek, MARGIN_F);
                bool p = v > 0.0f; tot += p ? v : 0.0f; cnt += (int)__popcll(__ballot(p)); }
            {   float d = gk - g4.z; float v = fmaf(copysignf(1.0f, d), e4.z - ek, MARGIN_F);
                bool p = v > 0.0f; tot += p ? v : 0.0f; cnt += (int)__popcll(__ballot(p)); }
            {   float d = gk - g4.w; float v = fmaf(copysignf(1.0f, d), e4.w - ek, MARGIN_F);
                bool p = v > 0.0f; tot += p ? v : 0.0f; cnt += (int)__popcll(__ballot(p)); }
        }
        // self-pair removal: lane with k in [j0,j0+80) and ek valid contributed exactly MARGIN
        bool self = (ek == ek) && (k >= j0) && (k < j0 + JLEN);
        tot -= self ? MARGIN_F : 0.0f;
        cnt -= (int)__popcll(__ballot(self));
    }

    // lane reduce (tot only; cnt is wave-uniform)
    for (int off = 32; off > 0; off >>= 1) tot += __shfl_down(tot, off, 64);

    __shared__ float wt[LTHR / 64];
    __shared__ int   wc[LTHR / 64];
    __shared__ int   sWinner;
    if (lane == 0) { wt[wid] = tot; wc[wid] = cnt; }
    __syncthreads();

    if (threadIdx.x == 0) {
        float T = 0.0f; int C = 0;
        #pragma unroll
        for (int w = 0; w < LTHR / 64; ++w) { T += wt[w]; C += wc[w]; }
        atomicExch(&pT[blockIdx.x], T);
        atomicExch(&pC[blockIdx.x], (float)C);
        __threadfence();                         // release
        unsigned old = atomicAdd(gate, 1u);
        sWinner = (old == (unsigned)(LBLK - 1)) ? 1 : 0;
    }
    __syncthreads();

    if (sWinner) {
        __threadfence();                         // acquire
        float T = 0.0f, C = 0.0f;
        if (threadIdx.x < LBLK) {
            T = atomicAdd(&pT[threadIdx.x], 0.0f);   // atomic loads (coherent point)
            C = atomicAdd(&pC[threadIdx.x], 0.0f);
        }
        for (int off = 32; off > 0; off >>= 1) {
            T += __shfl_down(T, off, 64);
            C += __shfl_down(C, off, 64);
        }
        __shared__ float ft[LTHR / 64], fc[LTHR / 64];
        if (lane == 0) { ft[wid] = T; fc[wid] = C; }
        __syncthreads();
        if (threadIdx.x == 0) {
            float Tt = 0.0f, Ct = 0.0f;
            #pragma unroll
            for (int w = 0; w < LTHR / 64; ++w) { Tt += ft[w]; Ct += fc[w]; }
            out[0] = (Ct > 0.0f) ? WEIGHT_F * Tt / Ct : 0.0f;
        }
    }
}

extern "C" void kernel_launch(void* const* d_in, const int* in_sizes, int n_in,
                              void* d_out, int out_size, void* d_ws, size_t ws_size,
                              hipStream_t stream) {
    const float* E  = (const float*)d_in[0];   // embeddings (320 x 129)
    const float* gt = (const float*)d_in[1];   // tree_distances (320 x 320)
    float* out = (float*)d_out;
    unsigned* gate = (unsigned*)d_ws;                         // 4 B, zeroed by kernel 1
    float* pT = (float*)((char*)d_ws + 256);                  // 256 f32
    float* pC = (float*)((char*)d_ws + 256 + LBLK * 4);       // 256 f32
    float* embp = (float*)((char*)d_ws + 4096);               // 320*320 f32 = 400 KB

    lorentz_kernel<<<NTRI, 256, 0, stream>>>(E, gt, embp, gate);
    loss_kernel<<<LBLK, LTHR, 0, stream>>>(embp, gt, gate, pT, pC, out);
}